// Round 1
// baseline (1848.466 us; speedup 1.0000x reference)
//
#include <hip/hip_runtime.h>
#include <hip/hip_bf16.h>
#include <math.h>

#define N_TOK 8192
#define H_DIM 1024
#define FF_DIM 4096
#define N_EXP 8
#define NPAIR (N_TOK * 2)
#define NPAIR_PAD (NPAIR + 128)

#define BM 128
#define BN 128
#define BK 32
#define LDSS 40   // bf16 elems: 32 + 8 pad -> 80B rows (16B aligned), max 2-way bank alias (free)

typedef short shortx8 __attribute__((ext_vector_type(8)));
typedef float floatx4 __attribute__((ext_vector_type(4)));

__device__ inline unsigned short f2b(float f) {
  unsigned int u = __float_as_uint(f);
  u += 0x7fffu + ((u >> 16) & 1u);
  return (unsigned short)(u >> 16);
}

// ---------- fp32 -> bf16 convert (hidden_states) ----------
__global__ void convert_bf16_kernel(const float* __restrict__ src,
                                    unsigned short* __restrict__ dst, int n8) {
  int i = blockIdx.x * blockDim.x + threadIdx.x;
  if (i >= n8) return;
  const float4* s = (const float4*)(src + (size_t)i * 8);
  float4 a = s[0], b = s[1];
  ushort4 lo, hi;
  lo.x = f2b(a.x); lo.y = f2b(a.y); lo.z = f2b(a.z); lo.w = f2b(a.w);
  hi.x = f2b(b.x); hi.y = f2b(b.y); hi.z = f2b(b.z); hi.w = f2b(b.w);
  ushort4* d = (ushort4*)(dst + (size_t)i * 8);
  d[0] = lo; d[1] = hi;
}

// ---------- router: logits, top-2, softmax ----------
__global__ void router_kernel(const float* __restrict__ x, const float* __restrict__ rw,
                              const float* __restrict__ rb, int* __restrict__ tki,
                              float* __restrict__ tkw, int* __restrict__ counts) {
  int t = blockIdx.x;
  int lane = threadIdx.x;
  const float* xr = x + (size_t)t * H_DIM;
  float p[N_EXP];
#pragma unroll
  for (int e = 0; e < N_EXP; e++) p[e] = 0.f;
  for (int h = lane; h < H_DIM; h += 64) {
    float xv = xr[h];
#pragma unroll
    for (int e = 0; e < N_EXP; e++) p[e] += xv * rw[e * H_DIM + h];
  }
#pragma unroll
  for (int m = 1; m < 64; m <<= 1) {
#pragma unroll
    for (int e = 0; e < N_EXP; e++) p[e] += __shfl_xor(p[e], m, 64);
  }
  if (lane == 0) {
#pragma unroll
    for (int e = 0; e < N_EXP; e++) p[e] += rb[e];
    int i0 = 0; float v0 = p[0];
#pragma unroll
    for (int e = 1; e < N_EXP; e++) if (p[e] > v0) { v0 = p[e]; i0 = e; }
    int i1 = -1; float v1 = -1e30f;
#pragma unroll
    for (int e = 0; e < N_EXP; e++) if (e != i0 && p[e] > v1) { v1 = p[e]; i1 = e; }
    float ex = expf(v1 - v0);
    float inv = 1.f / (1.f + ex);
    tki[2 * t] = i0; tki[2 * t + 1] = i1;
    tkw[2 * t] = inv; tkw[2 * t + 1] = ex * inv;
    atomicAdd(&counts[i0], 1);
    atomicAdd(&counts[i1], 1);
  }
}

// ---------- prefix over 8 experts ----------
__global__ void offsets_kernel(const int* __restrict__ counts, int* __restrict__ offsets,
                               int* __restrict__ cursors) {
  if (threadIdx.x == 0 && blockIdx.x == 0) {
    int off = 0;
    for (int e = 0; e < N_EXP; e++) { offsets[e] = off; cursors[e] = off; off += counts[e]; }
    offsets[N_EXP] = off;
  }
}

// ---------- build per-expert pair lists ----------
__global__ void place_kernel(const int* __restrict__ tki, const float* __restrict__ tkw,
                             int* __restrict__ cursors, int* __restrict__ pair_token,
                             float* __restrict__ pair_w, int* __restrict__ pair_pos) {
  int t = blockIdx.x * blockDim.x + threadIdx.x;
  if (t >= N_TOK) return;
#pragma unroll
  for (int k = 0; k < 2; k++) {
    int e = tki[2 * t + k];
    int pos = atomicAdd(&cursors[e], 1);
    pair_token[pos] = t;
    pair_w[pos] = tkw[2 * t + k];
    pair_pos[2 * t + k] = pos;
  }
}

// ---------- GEMM1: Y = gelu(Xg @ w1[e]^T + b1[e]) ----------
__global__ void gemm1_kernel(const unsigned short* __restrict__ Xb, const float* __restrict__ w1,
                             const float* __restrict__ b1, const int* __restrict__ pair_token,
                             const int* __restrict__ offsets, unsigned short* __restrict__ Y) {
  int e = blockIdx.z;
  int off = offsets[e];
  int cnt = offsets[e + 1] - off;
  int m0 = blockIdx.y * BM;
  if (m0 >= cnt) return;
  int n0 = blockIdx.x * BN;

  __shared__ unsigned short As[BM * LDSS];
  __shared__ unsigned short Bs[BN * LDSS];
  __shared__ int toks[BM];

  int tid = threadIdx.x;
  if (tid < BM) {
    int m = m0 + tid;
    toks[tid] = pair_token[off + (m < cnt ? m : cnt - 1)];
  }
  __syncthreads();

  floatx4 acc[4][4];
#pragma unroll
  for (int i = 0; i < 4; i++)
#pragma unroll
    for (int j = 0; j < 4; j++) acc[i][j] = (floatx4){0.f, 0.f, 0.f, 0.f};

  int wave = tid >> 6, lane = tid & 63;
  int wm = (wave & 1) * 64, wn = (wave >> 1) * 64;
  int lrow = lane & 15, lq = lane >> 4;

  for (int k0 = 0; k0 < H_DIM; k0 += BK) {
    // A staging: 128x32 bf16, 8 elems (16B) per chunk
    for (int c = tid; c < BM * BK / 8; c += 256) {
      int row = c >> 2, kc = (c & 3) << 3;
      uint4 v = *(const uint4*)(Xb + (size_t)toks[row] * H_DIM + k0 + kc);
      *(uint4*)&As[row * LDSS + kc] = v;
    }
    // B staging: 128x32 fp32 -> bf16
    for (int c = tid; c < BN * BK / 4; c += 256) {
      int row = c >> 3, kc = (c & 7) << 2;
      float4 v = *(const float4*)(w1 + ((size_t)e * FF_DIM + n0 + row) * H_DIM + k0 + kc);
      ushort4 bv; bv.x = f2b(v.x); bv.y = f2b(v.y); bv.z = f2b(v.z); bv.w = f2b(v.w);
      *(ushort4*)&Bs[row * LDSS + kc] = bv;
    }
    __syncthreads();
    shortx8 af[4], bf[4];
#pragma unroll
    for (int i = 0; i < 4; i++) af[i] = *(const shortx8*)&As[(wm + i * 16 + lrow) * LDSS + lq * 8];
#pragma unroll
    for (int j = 0; j < 4; j++) bf[j] = *(const shortx8*)&Bs[(wn + j * 16 + lrow) * LDSS + lq * 8];
#pragma unroll
    for (int i = 0; i < 4; i++)
#pragma unroll
      for (int j = 0; j < 4; j++)
        acc[i][j] = __builtin_amdgcn_mfma_f32_16x16x32_bf16(af[i], bf[j], acc[i][j], 0, 0, 0);
    __syncthreads();
  }

  // epilogue: bias + exact gelu -> bf16 Y
#pragma unroll
  for (int j = 0; j < 4; j++) {
    int col = n0 + wn + j * 16 + lrow;
    float bias = b1[(size_t)e * FF_DIM + col];
#pragma unroll
    for (int i = 0; i < 4; i++) {
#pragma unroll
      for (int r = 0; r < 4; r++) {
        int rm = wm + i * 16 + lq * 4 + r;
        if (m0 + rm < cnt) {
          float v = acc[i][j][r] + bias;
          v = 0.5f * v * (1.f + erff(v * 0.70710678118654752f));
          Y[(size_t)(off + m0 + rm) * FF_DIM + col] = f2b(v);
        }
      }
    }
  }
}

// ---------- GEMM2: Yout = (Y @ w2[e]^T + b2[e]) * pair_w ----------
__global__ void gemm2_kernel(const unsigned short* __restrict__ Y, const float* __restrict__ w2,
                             const float* __restrict__ b2, const float* __restrict__ pair_w,
                             const int* __restrict__ offsets, float* __restrict__ Yout) {
  int e = blockIdx.z;
  int off = offsets[e];
  int cnt = offsets[e + 1] - off;
  int m0 = blockIdx.y * BM;
  if (m0 >= cnt) return;
  int n0 = blockIdx.x * BN;

  __shared__ unsigned short As[BM * LDSS];
  __shared__ unsigned short Bs[BN * LDSS];

  int tid = threadIdx.x;
  floatx4 acc[4][4];
#pragma unroll
  for (int i = 0; i < 4; i++)
#pragma unroll
    for (int j = 0; j < 4; j++) acc[i][j] = (floatx4){0.f, 0.f, 0.f, 0.f};

  int wave = tid >> 6, lane = tid & 63;
  int wm = (wave & 1) * 64, wn = (wave >> 1) * 64;
  int lrow = lane & 15, lq = lane >> 4;

  for (int k0 = 0; k0 < FF_DIM; k0 += BK) {
    for (int c = tid; c < BM * BK / 8; c += 256) {
      int row = c >> 2, kc = (c & 3) << 3;
      uint4 v = *(const uint4*)(Y + (size_t)(off + m0 + row) * FF_DIM + k0 + kc);
      *(uint4*)&As[row * LDSS + kc] = v;
    }
    for (int c = tid; c < BN * BK / 4; c += 256) {
      int row = c >> 3, kc = (c & 7) << 2;
      float4 v = *(const float4*)(w2 + ((size_t)e * H_DIM + n0 + row) * FF_DIM + k0 + kc);
      ushort4 bv; bv.x = f2b(v.x); bv.y = f2b(v.y); bv.z = f2b(v.z); bv.w = f2b(v.w);
      *(ushort4*)&Bs[row * LDSS + kc] = bv;
    }
    __syncthreads();
    shortx8 af[4], bf[4];
#pragma unroll
    for (int i = 0; i < 4; i++) af[i] = *(const shortx8*)&As[(wm + i * 16 + lrow) * LDSS + lq * 8];
#pragma unroll
    for (int j = 0; j < 4; j++) bf[j] = *(const shortx8*)&Bs[(wn + j * 16 + lrow) * LDSS + lq * 8];
#pragma unroll
    for (int i = 0; i < 4; i++)
#pragma unroll
      for (int j = 0; j < 4; j++)
        acc[i][j] = __builtin_amdgcn_mfma_f32_16x16x32_bf16(af[i], bf[j], acc[i][j], 0, 0, 0);
    __syncthreads();
  }

#pragma unroll
  for (int j = 0; j < 4; j++) {
    int col = n0 + wn + j * 16 + lrow;
    float bias = b2[(size_t)e * H_DIM + col];
#pragma unroll
    for (int i = 0; i < 4; i++) {
#pragma unroll
      for (int r = 0; r < 4; r++) {
        int rm = wm + i * 16 + lq * 4 + r;
        if (m0 + rm < cnt) {
          int p = off + m0 + rm;
          float v = (acc[i][j][r] + bias) * pair_w[p];
          Yout[(size_t)p * H_DIM + col] = v;
        }
      }
    }
  }
}

// ---------- final: residual + combine 2 experts + layernorm ----------
__global__ void ln_kernel(const float* __restrict__ hidden, const float* __restrict__ Yout,
                          const int* __restrict__ pair_pos, const float* __restrict__ lnw,
                          const float* __restrict__ lnb, float* __restrict__ out) {
  int t = blockIdx.x;
  int tid = threadIdx.x;   // 256 threads, 4 floats each
  int p0 = pair_pos[2 * t], p1 = pair_pos[2 * t + 1];
  float4 hv = ((const float4*)(hidden + (size_t)t * H_DIM))[tid];
  float4 av = ((const float4*)(Yout + (size_t)p0 * H_DIM))[tid];
  float4 bv = ((const float4*)(Yout + (size_t)p1 * H_DIM))[tid];
  float x0 = hv.x + av.x + bv.x;
  float x1 = hv.y + av.y + bv.y;
  float x2 = hv.z + av.z + bv.z;
  float x3 = hv.w + av.w + bv.w;
  float s = x0 + x1 + x2 + x3;
  float ss = x0 * x0 + x1 * x1 + x2 * x2 + x3 * x3;
#pragma unroll
  for (int m = 1; m < 64; m <<= 1) {
    s += __shfl_xor(s, m, 64);
    ss += __shfl_xor(ss, m, 64);
  }
  __shared__ float red[8];
  int wave = tid >> 6, lane = tid & 63;
  if (lane == 0) { red[wave] = s; red[wave + 4] = ss; }
  __syncthreads();
  s = red[0] + red[1] + red[2] + red[3];
  ss = red[4] + red[5] + red[6] + red[7];
  float mu = s * (1.f / H_DIM);
  float var = ss * (1.f / H_DIM) - mu * mu;
  float rstd = rsqrtf(var + 1e-12f);
  int h = tid * 4;
  float4 o;
  o.x = (x0 - mu) * rstd * lnw[h + 0] + lnb[h + 0];
  o.y = (x1 - mu) * rstd * lnw[h + 1] + lnb[h + 1];
  o.z = (x2 - mu) * rstd * lnw[h + 2] + lnb[h + 2];
  o.w = (x3 - mu) * rstd * lnw[h + 3] + lnb[h + 3];
  ((float4*)(out + (size_t)t * H_DIM))[tid] = o;
}

extern "C" void kernel_launch(void* const* d_in, const int* in_sizes, int n_in,
                              void* d_out, int out_size, void* d_ws, size_t ws_size,
                              hipStream_t stream) {
  const float* hidden = (const float*)d_in[0];
  const float* rw     = (const float*)d_in[1];
  const float* rb     = (const float*)d_in[2];
  const float* w1     = (const float*)d_in[3];
  const float* b1     = (const float*)d_in[4];
  const float* w2     = (const float*)d_in[5];
  const float* b2     = (const float*)d_in[6];
  const float* lnw    = (const float*)d_in[7];
  const float* lnb    = (const float*)d_in[8];
  float* out = (float*)d_out;

  char* base = (char*)d_ws;
  size_t cur = 0;
  auto alloc = [&](size_t bytes) -> void* {
    void* r = base + cur;
    cur = (cur + bytes + 255) & ~(size_t)255;
    return r;
  };
  int* counts      = (int*)alloc(N_EXP * 4);
  int* offsets     = (int*)alloc((N_EXP + 1) * 4);
  int* cursors     = (int*)alloc(N_EXP * 4);
  int* tki         = (int*)alloc(NPAIR * 4);
  float* tkw       = (float*)alloc(NPAIR * 4);
  int* pair_token  = (int*)alloc(NPAIR_PAD * 4);
  float* pair_w    = (float*)alloc(NPAIR_PAD * 4);
  int* pair_pos    = (int*)alloc(NPAIR * 4);
  unsigned short* Xb = (unsigned short*)alloc((size_t)N_TOK * H_DIM * 2);
  unsigned short* Y  = (unsigned short*)alloc((size_t)NPAIR_PAD * FF_DIM * 2);
  float* Yout        = (float*)alloc((size_t)NPAIR_PAD * H_DIM * 4);

  hipMemsetAsync(counts, 0, N_EXP * 4, stream);
  convert_bf16_kernel<<<(N_TOK * H_DIM / 8 + 255) / 256, 256, 0, stream>>>(
      hidden, Xb, N_TOK * H_DIM / 8);
  router_kernel<<<N_TOK, 64, 0, stream>>>(hidden, rw, rb, tki, tkw, counts);
  offsets_kernel<<<1, 64, 0, stream>>>(counts, offsets, cursors);
  place_kernel<<<N_TOK / 256, 256, 0, stream>>>(tki, tkw, cursors, pair_token, pair_w, pair_pos);
  gemm1_kernel<<<dim3(FF_DIM / BN, (N_TOK + BM - 1) / BM, N_EXP), 256, 0, stream>>>(
      Xb, w1, b1, pair_token, offsets, Y);
  gemm2_kernel<<<dim3(H_DIM / BN, (N_TOK + BM - 1) / BM, N_EXP), 256, 0, stream>>>(
      Y, w2, b2, pair_w, offsets, Yout);
  ln_kernel<<<N_TOK, 256, 0, stream>>>(hidden, Yout, pair_pos, lnw, lnb, out);
}

// Round 2
// 1106.613 us; speedup vs baseline: 1.6704x; 1.6704x over previous
//
#include <hip/hip_runtime.h>
#include <hip/hip_bf16.h>
#include <math.h>

#define N_TOK 8192
#define H_DIM 1024
#define FF_DIM 4096
#define N_EXP 8
#define NPAIR (N_TOK * 2)
#define NPAIR_PAD (NPAIR + 128)

#define BM 128
#define BN 128
#define BK 64   // bf16 elems; tile = 128x64x2B = 16 KB, two tiles = 32 KB LDS

typedef unsigned short ushort_t;
typedef short shortx8 __attribute__((ext_vector_type(8)));
typedef float floatx4 __attribute__((ext_vector_type(4)));

__device__ inline unsigned short f2b(float f) {
  unsigned int u = __float_as_uint(f);
  u += 0x7fffu + ((u >> 16) & 1u);
  return (unsigned short)(u >> 16);
}

// async global->LDS, 16B per lane. LDS dest must be wave-uniform base; HW adds lane*16.
__device__ inline void async16(const void* g, void* l) {
  __builtin_amdgcn_global_load_lds(
      (const __attribute__((address_space(1))) unsigned int*)g,
      (__attribute__((address_space(3))) unsigned int*)l, 16, 0, 0);
}

// ---------- fp32 -> bf16 convert (hidden / w1 / w2) ----------
__global__ void convert_bf16_kernel(const float* __restrict__ src,
                                    ushort_t* __restrict__ dst, int n8) {
  int i = blockIdx.x * blockDim.x + threadIdx.x;
  if (i >= n8) return;
  const float4* s = (const float4*)(src + (size_t)i * 8);
  float4 a = s[0], b = s[1];
  ushort4 lo, hi;
  lo.x = f2b(a.x); lo.y = f2b(a.y); lo.z = f2b(a.z); lo.w = f2b(a.w);
  hi.x = f2b(b.x); hi.y = f2b(b.y); hi.z = f2b(b.z); hi.w = f2b(b.w);
  ushort4* d = (ushort4*)(dst + (size_t)i * 8);
  d[0] = lo; d[1] = hi;
}

// ---------- router: logits, top-2, softmax ----------
__global__ void router_kernel(const float* __restrict__ x, const float* __restrict__ rw,
                              const float* __restrict__ rb, int* __restrict__ tki,
                              float* __restrict__ tkw, int* __restrict__ counts) {
  int t = blockIdx.x;
  int lane = threadIdx.x;
  const float* xr = x + (size_t)t * H_DIM;
  float p[N_EXP];
#pragma unroll
  for (int e = 0; e < N_EXP; e++) p[e] = 0.f;
  for (int h = lane; h < H_DIM; h += 64) {
    float xv = xr[h];
#pragma unroll
    for (int e = 0; e < N_EXP; e++) p[e] += xv * rw[e * H_DIM + h];
  }
#pragma unroll
  for (int m = 1; m < 64; m <<= 1) {
#pragma unroll
    for (int e = 0; e < N_EXP; e++) p[e] += __shfl_xor(p[e], m, 64);
  }
  if (lane == 0) {
#pragma unroll
    for (int e = 0; e < N_EXP; e++) p[e] += rb[e];
    int i0 = 0; float v0 = p[0];
#pragma unroll
    for (int e = 1; e < N_EXP; e++) if (p[e] > v0) { v0 = p[e]; i0 = e; }
    int i1 = -1; float v1 = -1e30f;
#pragma unroll
    for (int e = 0; e < N_EXP; e++) if (e != i0 && p[e] > v1) { v1 = p[e]; i1 = e; }
    float ex = expf(v1 - v0);
    float inv = 1.f / (1.f + ex);
    tki[2 * t] = i0; tki[2 * t + 1] = i1;
    tkw[2 * t] = inv; tkw[2 * t + 1] = ex * inv;
    atomicAdd(&counts[i0], 1);
    atomicAdd(&counts[i1], 1);
  }
}

// ---------- prefix over 8 experts ----------
__global__ void offsets_kernel(const int* __restrict__ counts, int* __restrict__ offsets,
                               int* __restrict__ cursors) {
  if (threadIdx.x == 0 && blockIdx.x == 0) {
    int off = 0;
    for (int e = 0; e < N_EXP; e++) { offsets[e] = off; cursors[e] = off; off += counts[e]; }
    offsets[N_EXP] = off;
  }
}

// ---------- build per-expert pair lists ----------
__global__ void place_kernel(const int* __restrict__ tki, const float* __restrict__ tkw,
                             int* __restrict__ cursors, int* __restrict__ pair_token,
                             float* __restrict__ pair_w, int* __restrict__ pair_pos) {
  int t = blockIdx.x * blockDim.x + threadIdx.x;
  if (t >= N_TOK) return;
#pragma unroll
  for (int k = 0; k < 2; k++) {
    int e = tki[2 * t + k];
    int pos = atomicAdd(&cursors[e], 1);
    pair_token[pos] = t;
    pair_w[pos] = tkw[2 * t + k];
    pair_pos[2 * t + k] = pos;
  }
}

// ---------- GEMM1: Y = gelu(Xg @ w1[e]^T + b1[e]) ----------
// LDS layout: 16B chunks; chunk (row, c) holds global k-chunk (c ^ (row&7)).
// Staging via global_load_lds is contiguous per wave; ds_read_b128 lands 2-way max.
__global__ __launch_bounds__(256, 2)
void gemm1_kernel(const ushort_t* __restrict__ Xb, const ushort_t* __restrict__ w1b,
                  const float* __restrict__ b1, const int* __restrict__ pair_token,
                  const int* __restrict__ offsets, ushort_t* __restrict__ Y) {
  int e = blockIdx.z;
  int off = offsets[e];
  int cnt = offsets[e + 1] - off;
  int m0 = blockIdx.y * BM;
  if (m0 >= cnt) return;
  int n0 = blockIdx.x * BN;

  __shared__ ushort_t As[BM * BK];
  __shared__ ushort_t Bs[BN * BK];

  int tid = threadIdx.x;
  int w = tid >> 6, l = tid & 63;
  int lr8 = l >> 3;                       // row-within-8 of this lane's 16B chunk
  int lcol = ((l & 7) ^ lr8) << 3;        // swizzled global k-chunk (elements)

  const ushort_t* gA[4];
  const ushort_t* gB[4];
  ushort_t* lA[4];
  ushort_t* lB[4];
#pragma unroll
  for (int it = 0; it < 4; it++) {
    int row = (w * 4 + it) * 8 + lr8;
    int m = m0 + row; if (m >= cnt) m = cnt - 1;
    int tok = pair_token[off + m];
    gA[it] = Xb + (size_t)tok * H_DIM + lcol;
    gB[it] = w1b + ((size_t)e * FF_DIM + n0 + row) * H_DIM + lcol;
    lA[it] = As + (w * 4 + it) * 512;
    lB[it] = Bs + (w * 4 + it) * 512;
  }

  floatx4 acc[4][4];
#pragma unroll
  for (int i = 0; i < 4; i++)
#pragma unroll
    for (int j = 0; j < 4; j++) acc[i][j] = (floatx4){0.f, 0.f, 0.f, 0.f};

  int wm = (w & 1) * 64, wn = (w >> 1) * 64;
  int lrow = l & 15, lq = l >> 4, sx = l & 7;

  for (int k0 = 0; k0 < H_DIM; k0 += BK) {
#pragma unroll
    for (int it = 0; it < 4; it++) async16(gA[it] + k0, lA[it]);
#pragma unroll
    for (int it = 0; it < 4; it++) async16(gB[it] + k0, lB[it]);
    __syncthreads();
#pragma unroll
    for (int kkh = 0; kkh < 2; kkh++) {
      int c = (((lq + 4 * kkh) ^ sx) << 3);
      shortx8 af[4], bf[4];
#pragma unroll
      for (int i = 0; i < 4; i++) {
        af[i] = *(const shortx8*)&As[(wm + i * 16 + lrow) * BK + c];
        bf[i] = *(const shortx8*)&Bs[(wn + i * 16 + lrow) * BK + c];
      }
#pragma unroll
      for (int i = 0; i < 4; i++)
#pragma unroll
        for (int j = 0; j < 4; j++)
          acc[i][j] = __builtin_amdgcn_mfma_f32_16x16x32_bf16(af[i], bf[j], acc[i][j], 0, 0, 0);
    }
    __syncthreads();
  }

  // epilogue: bias + exact gelu -> bf16 Y
#pragma unroll
  for (int j = 0; j < 4; j++) {
    int col = n0 + wn + j * 16 + lrow;
    float bias = b1[(size_t)e * FF_DIM + col];
#pragma unroll
    for (int i = 0; i < 4; i++) {
#pragma unroll
      for (int r = 0; r < 4; r++) {
        int rm = wm + i * 16 + lq * 4 + r;
        if (m0 + rm < cnt) {
          float v = acc[i][j][r] + bias;
          v = 0.5f * v * (1.f + erff(v * 0.70710678118654752f));
          Y[(size_t)(off + m0 + rm) * FF_DIM + col] = f2b(v);
        }
      }
    }
  }
}

// ---------- GEMM2: Yout = (Y @ w2[e]^T + b2[e]) * pair_w ----------
__global__ __launch_bounds__(256, 2)
void gemm2_kernel(const ushort_t* __restrict__ Y, const ushort_t* __restrict__ w2b,
                  const float* __restrict__ b2, const float* __restrict__ pair_w,
                  const int* __restrict__ offsets, float* __restrict__ Yout) {
  int e = blockIdx.z;
  int off = offsets[e];
  int cnt = offsets[e + 1] - off;
  int m0 = blockIdx.y * BM;
  if (m0 >= cnt) return;
  int n0 = blockIdx.x * BN;

  __shared__ ushort_t As[BM * BK];
  __shared__ ushort_t Bs[BN * BK];

  int tid = threadIdx.x;
  int w = tid >> 6, l = tid & 63;
  int lr8 = l >> 3;
  int lcol = ((l & 7) ^ lr8) << 3;

  const ushort_t* gA[4];
  const ushort_t* gB[4];
  ushort_t* lA[4];
  ushort_t* lB[4];
#pragma unroll
  for (int it = 0; it < 4; it++) {
    int row = (w * 4 + it) * 8 + lr8;
    gA[it] = Y + (size_t)(off + m0 + row) * FF_DIM + lcol;   // pad rows safe: NPAIR_PAD slack
    gB[it] = w2b + ((size_t)e * H_DIM + n0 + row) * FF_DIM + lcol;
    lA[it] = As + (w * 4 + it) * 512;
    lB[it] = Bs + (w * 4 + it) * 512;
  }

  floatx4 acc[4][4];
#pragma unroll
  for (int i = 0; i < 4; i++)
#pragma unroll
    for (int j = 0; j < 4; j++) acc[i][j] = (floatx4){0.f, 0.f, 0.f, 0.f};

  int wm = (w & 1) * 64, wn = (w >> 1) * 64;
  int lrow = l & 15, lq = l >> 4, sx = l & 7;

  for (int k0 = 0; k0 < FF_DIM; k0 += BK) {
#pragma unroll
    for (int it = 0; it < 4; it++) async16(gA[it] + k0, lA[it]);
#pragma unroll
    for (int it = 0; it < 4; it++) async16(gB[it] + k0, lB[it]);
    __syncthreads();
#pragma unroll
    for (int kkh = 0; kkh < 2; kkh++) {
      int c = (((lq + 4 * kkh) ^ sx) << 3);
      shortx8 af[4], bf[4];
#pragma unroll
      for (int i = 0; i < 4; i++) {
        af[i] = *(const shortx8*)&As[(wm + i * 16 + lrow) * BK + c];
        bf[i] = *(const shortx8*)&Bs[(wn + i * 16 + lrow) * BK + c];
      }
#pragma unroll
      for (int i = 0; i < 4; i++)
#pragma unroll
        for (int j = 0; j < 4; j++)
          acc[i][j] = __builtin_amdgcn_mfma_f32_16x16x32_bf16(af[i], bf[j], acc[i][j], 0, 0, 0);
    }
    __syncthreads();
  }

#pragma unroll
  for (int j = 0; j < 4; j++) {
    int col = n0 + wn + j * 16 + lrow;
    float bias = b2[(size_t)e * H_DIM + col];
#pragma unroll
    for (int i = 0; i < 4; i++) {
#pragma unroll
      for (int r = 0; r < 4; r++) {
        int rm = wm + i * 16 + lq * 4 + r;
        if (m0 + rm < cnt) {
          int p = off + m0 + rm;
          float v = (acc[i][j][r] + bias) * pair_w[p];
          Yout[(size_t)p * H_DIM + col] = v;
        }
      }
    }
  }
}

// ---------- final: residual + combine 2 experts + layernorm ----------
__global__ void ln_kernel(const float* __restrict__ hidden, const float* __restrict__ Yout,
                          const int* __restrict__ pair_pos, const float* __restrict__ lnw,
                          const float* __restrict__ lnb, float* __restrict__ out) {
  int t = blockIdx.x;
  int tid = threadIdx.x;   // 256 threads, 4 floats each
  int p0 = pair_pos[2 * t], p1 = pair_pos[2 * t + 1];
  float4 hv = ((const float4*)(hidden + (size_t)t * H_DIM))[tid];
  float4 av = ((const float4*)(Yout + (size_t)p0 * H_DIM))[tid];
  float4 bv = ((const float4*)(Yout + (size_t)p1 * H_DIM))[tid];
  float x0 = hv.x + av.x + bv.x;
  float x1 = hv.y + av.y + bv.y;
  float x2 = hv.z + av.z + bv.z;
  float x3 = hv.w + av.w + bv.w;
  float s = x0 + x1 + x2 + x3;
  float ss = x0 * x0 + x1 * x1 + x2 * x2 + x3 * x3;
#pragma unroll
  for (int m = 1; m < 64; m <<= 1) {
    s += __shfl_xor(s, m, 64);
    ss += __shfl_xor(ss, m, 64);
  }
  __shared__ float red[8];
  int wave = tid >> 6, lane = tid & 63;
  if (lane == 0) { red[wave] = s; red[wave + 4] = ss; }
  __syncthreads();
  s = red[0] + red[1] + red[2] + red[3];
  ss = red[4] + red[5] + red[6] + red[7];
  float mu = s * (1.f / H_DIM);
  float var = ss * (1.f / H_DIM) - mu * mu;
  float rstd = rsqrtf(var + 1e-12f);
  int h = tid * 4;
  float4 o;
  o.x = (x0 - mu) * rstd * lnw[h + 0] + lnb[h + 0];
  o.y = (x1 - mu) * rstd * lnw[h + 1] + lnb[h + 1];
  o.z = (x2 - mu) * rstd * lnw[h + 2] + lnb[h + 2];
  o.w = (x3 - mu) * rstd * lnw[h + 3] + lnb[h + 3];
  ((float4*)(out + (size_t)t * H_DIM))[tid] = o;
}

extern "C" void kernel_launch(void* const* d_in, const int* in_sizes, int n_in,
                              void* d_out, int out_size, void* d_ws, size_t ws_size,
                              hipStream_t stream) {
  const float* hidden = (const float*)d_in[0];
  const float* rw     = (const float*)d_in[1];
  const float* rb     = (const float*)d_in[2];
  const float* w1     = (const float*)d_in[3];
  const float* b1     = (const float*)d_in[4];
  const float* w2     = (const float*)d_in[5];
  const float* b2     = (const float*)d_in[6];
  const float* lnw    = (const float*)d_in[7];
  const float* lnb    = (const float*)d_in[8];
  float* out = (float*)d_out;

  char* base = (char*)d_ws;
  size_t cur = 0;
  auto alloc = [&](size_t bytes) -> void* {
    void* r = base + cur;
    cur = (cur + bytes + 255) & ~(size_t)255;
    return r;
  };
  int* counts      = (int*)alloc(N_EXP * 4);
  int* offsets     = (int*)alloc((N_EXP + 1) * 4);
  int* cursors     = (int*)alloc(N_EXP * 4);
  int* tki         = (int*)alloc(NPAIR * 4);
  float* tkw       = (float*)alloc(NPAIR * 4);
  int* pair_token  = (int*)alloc(NPAIR_PAD * 4);
  float* pair_w    = (float*)alloc(NPAIR_PAD * 4);
  int* pair_pos    = (int*)alloc(NPAIR * 4);
  ushort_t* Xb  = (ushort_t*)alloc((size_t)N_TOK * H_DIM * 2);
  ushort_t* Y   = (ushort_t*)alloc((size_t)NPAIR_PAD * FF_DIM * 2);
  ushort_t* w2b = (ushort_t*)alloc((size_t)N_EXP * H_DIM * FF_DIM * 2);
  // alias: w1b is dead after gemm1; Yout written by gemm2 afterwards (same stream).
  size_t region = (size_t)NPAIR_PAD * H_DIM * 4;  // 67.6 MB >= w1b's 64 MB
  char* rg = (char*)alloc(region);
  ushort_t* w1b = (ushort_t*)rg;
  float* Yout   = (float*)rg;

  hipMemsetAsync(counts, 0, N_EXP * 4, stream);
  convert_bf16_kernel<<<(N_TOK * H_DIM / 8 + 255) / 256, 256, 0, stream>>>(
      hidden, Xb, N_TOK * H_DIM / 8);
  convert_bf16_kernel<<<(N_EXP * FF_DIM * H_DIM / 8 + 255) / 256, 256, 0, stream>>>(
      w1, w1b, N_EXP * FF_DIM * H_DIM / 8);
  convert_bf16_kernel<<<(N_EXP * H_DIM * FF_DIM / 8 + 255) / 256, 256, 0, stream>>>(
      w2, w2b, N_EXP * H_DIM * FF_DIM / 8);
  router_kernel<<<N_TOK, 64, 0, stream>>>(hidden, rw, rb, tki, tkw, counts);
  offsets_kernel<<<1, 64, 0, stream>>>(counts, offsets, cursors);
  place_kernel<<<N_TOK / 256, 256, 0, stream>>>(tki, tkw, cursors, pair_token, pair_w, pair_pos);
  gemm1_kernel<<<dim3(FF_DIM / BN, (N_TOK + BM - 1) / BM, N_EXP), 256, 0, stream>>>(
      Xb, w1b, b1, pair_token, offsets, Y);
  gemm2_kernel<<<dim3(H_DIM / BN, (N_TOK + BM - 1) / BM, N_EXP), 256, 0, stream>>>(
      Y, w2b, b2, pair_w, offsets, Yout);
  ln_kernel<<<N_TOK, 256, 0, stream>>>(hidden, Yout, pair_pos, lnw, lnb, out);
}

// Round 3
// 1082.704 us; speedup vs baseline: 1.7073x; 1.0221x over previous
//
#include <hip/hip_runtime.h>
#include <hip/hip_bf16.h>
#include <math.h>

#define N_TOK 8192
#define H_DIM 1024
#define FF_DIM 4096
#define N_EXP 8
#define NPAIR (N_TOK * 2)
#define NPAIR_PAD (NPAIR + 128)

#define BM 128
#define BN 128
#define BK 64   // bf16 elems; tile = 128x64x2B = 16 KB, two tiles = 32 KB LDS

typedef unsigned short ushort_t;
typedef short shortx8 __attribute__((ext_vector_type(8)));
typedef float floatx4 __attribute__((ext_vector_type(4)));

__device__ inline unsigned short f2b(float f) {
  unsigned int u = __float_as_uint(f);
  u += 0x7fffu + ((u >> 16) & 1u);
  return (unsigned short)(u >> 16);
}

__device__ inline float b2f(ushort_t b) {
  return __uint_as_float(((unsigned int)b) << 16);
}

// tanh-approx GELU: max |err| vs exact erf-gelu ~3e-4, ~10 VALU ops.
__device__ inline float fast_gelu(float x) {
  float u = 0.7978845608f * x * (1.f + 0.044715f * x * x);
  float au = fabsf(u);
  float e = __expf(-2.f * au);
  float t = (1.f - e) / (1.f + e);       // tanh(|u|)
  t = copysignf(t, u);
  return 0.5f * x * (1.f + t);
}

// async global->LDS, 16B per lane. LDS dest must be wave-uniform base; HW adds lane*16.
__device__ inline void async16(const void* g, void* l) {
  __builtin_amdgcn_global_load_lds(
      (const __attribute__((address_space(1))) unsigned int*)g,
      (__attribute__((address_space(3))) unsigned int*)l, 16, 0, 0);
}

// ---------- fp32 -> bf16 convert (hidden / w1 / w2) ----------
__global__ void convert_bf16_kernel(const float* __restrict__ src,
                                    ushort_t* __restrict__ dst, int n8) {
  int i = blockIdx.x * blockDim.x + threadIdx.x;
  if (i >= n8) return;
  const float4* s = (const float4*)(src + (size_t)i * 8);
  float4 a = s[0], b = s[1];
  ushort4 lo, hi;
  lo.x = f2b(a.x); lo.y = f2b(a.y); lo.z = f2b(a.z); lo.w = f2b(a.w);
  hi.x = f2b(b.x); hi.y = f2b(b.y); hi.z = f2b(b.z); hi.w = f2b(b.w);
  ushort4* d = (ushort4*)(dst + (size_t)i * 8);
  d[0] = lo; d[1] = hi;
}

// ---------- router: logits, top-2, softmax ----------
__global__ void router_kernel(const float* __restrict__ x, const float* __restrict__ rw,
                              const float* __restrict__ rb, int* __restrict__ tki,
                              float* __restrict__ tkw, int* __restrict__ counts) {
  int t = blockIdx.x;
  int lane = threadIdx.x;
  const float* xr = x + (size_t)t * H_DIM;
  float p[N_EXP];
#pragma unroll
  for (int e = 0; e < N_EXP; e++) p[e] = 0.f;
  for (int h = lane; h < H_DIM; h += 64) {
    float xv = xr[h];
#pragma unroll
    for (int e = 0; e < N_EXP; e++) p[e] += xv * rw[e * H_DIM + h];
  }
#pragma unroll
  for (int m = 1; m < 64; m <<= 1) {
#pragma unroll
    for (int e = 0; e < N_EXP; e++) p[e] += __shfl_xor(p[e], m, 64);
  }
  if (lane == 0) {
#pragma unroll
    for (int e = 0; e < N_EXP; e++) p[e] += rb[e];
    int i0 = 0; float v0 = p[0];
#pragma unroll
    for (int e = 1; e < N_EXP; e++) if (p[e] > v0) { v0 = p[e]; i0 = e; }
    int i1 = -1; float v1 = -1e30f;
#pragma unroll
    for (int e = 0; e < N_EXP; e++) if (e != i0 && p[e] > v1) { v1 = p[e]; i1 = e; }
    float ex = expf(v1 - v0);
    float inv = 1.f / (1.f + ex);
    tki[2 * t] = i0; tki[2 * t + 1] = i1;
    tkw[2 * t] = inv; tkw[2 * t + 1] = ex * inv;
    atomicAdd(&counts[i0], 1);
    atomicAdd(&counts[i1], 1);
  }
}

// ---------- prefix over 8 experts ----------
__global__ void offsets_kernel(const int* __restrict__ counts, int* __restrict__ offsets,
                               int* __restrict__ cursors) {
  if (threadIdx.x == 0 && blockIdx.x == 0) {
    int off = 0;
    for (int e = 0; e < N_EXP; e++) { offsets[e] = off; cursors[e] = off; off += counts[e]; }
    offsets[N_EXP] = off;
  }
}

// ---------- build per-expert pair lists ----------
__global__ void place_kernel(const int* __restrict__ tki, const float* __restrict__ tkw,
                             int* __restrict__ cursors, int* __restrict__ pair_token,
                             float* __restrict__ pair_w, int* __restrict__ pair_pos) {
  int t = blockIdx.x * blockDim.x + threadIdx.x;
  if (t >= N_TOK) return;
#pragma unroll
  for (int k = 0; k < 2; k++) {
    int e = tki[2 * t + k];
    int pos = atomicAdd(&cursors[e], 1);
    pair_token[pos] = t;
    pair_w[pos] = tkw[2 * t + k];
    pair_pos[2 * t + k] = pos;
  }
}

// ---------- GEMM1: Y = gelu(Xg @ w1[e]^T + b1[e]) ----------
// LDS layout: 16B chunks; chunk (row, c) holds global k-chunk (c ^ (row&7)).
// Staging via global_load_lds is contiguous per wave; ds_read_b128 lands 2-way max.
__global__ __launch_bounds__(256, 2)
void gemm1_kernel(const ushort_t* __restrict__ Xb, const ushort_t* __restrict__ w1b,
                  const float* __restrict__ b1, const int* __restrict__ pair_token,
                  const int* __restrict__ offsets, ushort_t* __restrict__ Y) {
  int e = blockIdx.z;
  int off = offsets[e];
  int cnt = offsets[e + 1] - off;
  int m0 = blockIdx.y * BM;
  if (m0 >= cnt) return;
  int n0 = blockIdx.x * BN;

  __shared__ ushort_t As[BM * BK];
  __shared__ ushort_t Bs[BN * BK];

  int tid = threadIdx.x;
  int w = tid >> 6, l = tid & 63;
  int lr8 = l >> 3;                       // row-within-8 of this lane's 16B chunk
  int lcol = ((l & 7) ^ lr8) << 3;        // swizzled global k-chunk (elements)

  const ushort_t* gA[4];
  const ushort_t* gB[4];
  ushort_t* lA[4];
  ushort_t* lB[4];
#pragma unroll
  for (int it = 0; it < 4; it++) {
    int row = (w * 4 + it) * 8 + lr8;
    int m = m0 + row; if (m >= cnt) m = cnt - 1;
    int tok = pair_token[off + m];
    gA[it] = Xb + (size_t)tok * H_DIM + lcol;
    gB[it] = w1b + ((size_t)e * FF_DIM + n0 + row) * H_DIM + lcol;
    lA[it] = As + (w * 4 + it) * 512;
    lB[it] = Bs + (w * 4 + it) * 512;
  }

  floatx4 acc[4][4];
#pragma unroll
  for (int i = 0; i < 4; i++)
#pragma unroll
    for (int j = 0; j < 4; j++) acc[i][j] = (floatx4){0.f, 0.f, 0.f, 0.f};

  int wm = (w & 1) * 64, wn = (w >> 1) * 64;
  int lrow = l & 15, lq = l >> 4, sx = l & 7;

  for (int k0 = 0; k0 < H_DIM; k0 += BK) {
#pragma unroll
    for (int it = 0; it < 4; it++) async16(gA[it] + k0, lA[it]);
#pragma unroll
    for (int it = 0; it < 4; it++) async16(gB[it] + k0, lB[it]);
    __syncthreads();
#pragma unroll
    for (int kkh = 0; kkh < 2; kkh++) {
      int c = (((lq + 4 * kkh) ^ sx) << 3);
      shortx8 af[4], bf[4];
#pragma unroll
      for (int i = 0; i < 4; i++) {
        af[i] = *(const shortx8*)&As[(wm + i * 16 + lrow) * BK + c];
        bf[i] = *(const shortx8*)&Bs[(wn + i * 16 + lrow) * BK + c];
      }
#pragma unroll
      for (int i = 0; i < 4; i++)
#pragma unroll
        for (int j = 0; j < 4; j++)
          acc[i][j] = __builtin_amdgcn_mfma_f32_16x16x32_bf16(af[i], bf[j], acc[i][j], 0, 0, 0);
    }
    __syncthreads();
  }

  // epilogue: bias + fast gelu -> bf16 Y
#pragma unroll
  for (int j = 0; j < 4; j++) {
    int col = n0 + wn + j * 16 + lrow;
    float bias = b1[(size_t)e * FF_DIM + col];
#pragma unroll
    for (int i = 0; i < 4; i++) {
#pragma unroll
      for (int r = 0; r < 4; r++) {
        int rm = wm + i * 16 + lq * 4 + r;
        if (m0 + rm < cnt) {
          float v = fast_gelu(acc[i][j][r] + bias);
          Y[(size_t)(off + m0 + rm) * FF_DIM + col] = f2b(v);
        }
      }
    }
  }
}

// ---------- GEMM2: Yout(bf16) = (Y @ w2[e]^T + b2[e]) * pair_w ----------
__global__ __launch_bounds__(256, 2)
void gemm2_kernel(const ushort_t* __restrict__ Y, const ushort_t* __restrict__ w2b,
                  const float* __restrict__ b2, const float* __restrict__ pair_w,
                  const int* __restrict__ offsets, ushort_t* __restrict__ Yout) {
  int e = blockIdx.z;
  int off = offsets[e];
  int cnt = offsets[e + 1] - off;
  int m0 = blockIdx.y * BM;
  if (m0 >= cnt) return;
  int n0 = blockIdx.x * BN;

  __shared__ ushort_t As[BM * BK];
  __shared__ ushort_t Bs[BN * BK];

  int tid = threadIdx.x;
  int w = tid >> 6, l = tid & 63;
  int lr8 = l >> 3;
  int lcol = ((l & 7) ^ lr8) << 3;

  const ushort_t* gA[4];
  const ushort_t* gB[4];
  ushort_t* lA[4];
  ushort_t* lB[4];
#pragma unroll
  for (int it = 0; it < 4; it++) {
    int row = (w * 4 + it) * 8 + lr8;
    gA[it] = Y + (size_t)(off + m0 + row) * FF_DIM + lcol;   // pad rows safe: NPAIR_PAD slack
    gB[it] = w2b + ((size_t)e * H_DIM + n0 + row) * FF_DIM + lcol;
    lA[it] = As + (w * 4 + it) * 512;
    lB[it] = Bs + (w * 4 + it) * 512;
  }

  floatx4 acc[4][4];
#pragma unroll
  for (int i = 0; i < 4; i++)
#pragma unroll
    for (int j = 0; j < 4; j++) acc[i][j] = (floatx4){0.f, 0.f, 0.f, 0.f};

  int wm = (w & 1) * 64, wn = (w >> 1) * 64;
  int lrow = l & 15, lq = l >> 4, sx = l & 7;

  for (int k0 = 0; k0 < FF_DIM; k0 += BK) {
#pragma unroll
    for (int it = 0; it < 4; it++) async16(gA[it] + k0, lA[it]);
#pragma unroll
    for (int it = 0; it < 4; it++) async16(gB[it] + k0, lB[it]);
    __syncthreads();
#pragma unroll
    for (int kkh = 0; kkh < 2; kkh++) {
      int c = (((lq + 4 * kkh) ^ sx) << 3);
      shortx8 af[4], bf[4];
#pragma unroll
      for (int i = 0; i < 4; i++) {
        af[i] = *(const shortx8*)&As[(wm + i * 16 + lrow) * BK + c];
        bf[i] = *(const shortx8*)&Bs[(wn + i * 16 + lrow) * BK + c];
      }
#pragma unroll
      for (int i = 0; i < 4; i++)
#pragma unroll
        for (int j = 0; j < 4; j++)
          acc[i][j] = __builtin_amdgcn_mfma_f32_16x16x32_bf16(af[i], bf[j], acc[i][j], 0, 0, 0);
    }
    __syncthreads();
  }

#pragma unroll
  for (int j = 0; j < 4; j++) {
    int col = n0 + wn + j * 16 + lrow;
    float bias = b2[(size_t)e * H_DIM + col];
#pragma unroll
    for (int i = 0; i < 4; i++) {
#pragma unroll
      for (int r = 0; r < 4; r++) {
        int rm = wm + i * 16 + lq * 4 + r;
        if (m0 + rm < cnt) {
          int p = off + m0 + rm;
          float v = (acc[i][j][r] + bias) * pair_w[p];
          Yout[(size_t)p * H_DIM + col] = f2b(v);
        }
      }
    }
  }
}

// ---------- final: residual + combine 2 experts + layernorm ----------
__global__ void ln_kernel(const float* __restrict__ hidden, const ushort_t* __restrict__ Yout,
                          const int* __restrict__ pair_pos, const float* __restrict__ lnw,
                          const float* __restrict__ lnb, float* __restrict__ out) {
  int t = blockIdx.x;
  int tid = threadIdx.x;   // 256 threads, 4 floats each
  int p0 = pair_pos[2 * t], p1 = pair_pos[2 * t + 1];
  float4 hv = ((const float4*)(hidden + (size_t)t * H_DIM))[tid];
  ushort4 au = ((const ushort4*)(Yout + (size_t)p0 * H_DIM))[tid];
  ushort4 bu = ((const ushort4*)(Yout + (size_t)p1 * H_DIM))[tid];
  float x0 = hv.x + b2f(au.x) + b2f(bu.x);
  float x1 = hv.y + b2f(au.y) + b2f(bu.y);
  float x2 = hv.z + b2f(au.z) + b2f(bu.z);
  float x3 = hv.w + b2f(au.w) + b2f(bu.w);
  float s = x0 + x1 + x2 + x3;
  float ss = x0 * x0 + x1 * x1 + x2 * x2 + x3 * x3;
#pragma unroll
  for (int m = 1; m < 64; m <<= 1) {
    s += __shfl_xor(s, m, 64);
    ss += __shfl_xor(ss, m, 64);
  }
  __shared__ float red[8];
  int wave = tid >> 6, lane = tid & 63;
  if (lane == 0) { red[wave] = s; red[wave + 4] = ss; }
  __syncthreads();
  s = red[0] + red[1] + red[2] + red[3];
  ss = red[4] + red[5] + red[6] + red[7];
  float mu = s * (1.f / H_DIM);
  float var = ss * (1.f / H_DIM) - mu * mu;
  float rstd = rsqrtf(var + 1e-12f);
  int h = tid * 4;
  float4 o;
  o.x = (x0 - mu) * rstd * lnw[h + 0] + lnb[h + 0];
  o.y = (x1 - mu) * rstd * lnw[h + 1] + lnb[h + 1];
  o.z = (x2 - mu) * rstd * lnw[h + 2] + lnb[h + 2];
  o.w = (x3 - mu) * rstd * lnw[h + 3] + lnb[h + 3];
  ((float4*)(out + (size_t)t * H_DIM))[tid] = o;
}

extern "C" void kernel_launch(void* const* d_in, const int* in_sizes, int n_in,
                              void* d_out, int out_size, void* d_ws, size_t ws_size,
                              hipStream_t stream) {
  const float* hidden = (const float*)d_in[0];
  const float* rw     = (const float*)d_in[1];
  const float* rb     = (const float*)d_in[2];
  const float* w1     = (const float*)d_in[3];
  const float* b1     = (const float*)d_in[4];
  const float* w2     = (const float*)d_in[5];
  const float* b2     = (const float*)d_in[6];
  const float* lnw    = (const float*)d_in[7];
  const float* lnb    = (const float*)d_in[8];
  float* out = (float*)d_out;

  char* base = (char*)d_ws;
  size_t cur = 0;
  auto alloc = [&](size_t bytes) -> void* {
    void* r = base + cur;
    cur = (cur + bytes + 255) & ~(size_t)255;
    return r;
  };
  int* counts      = (int*)alloc(N_EXP * 4);
  int* offsets     = (int*)alloc((N_EXP + 1) * 4);
  int* cursors     = (int*)alloc(N_EXP * 4);
  int* tki         = (int*)alloc(NPAIR * 4);
  float* tkw       = (float*)alloc(NPAIR * 4);
  int* pair_token  = (int*)alloc(NPAIR_PAD * 4);
  float* pair_w    = (float*)alloc(NPAIR_PAD * 4);
  int* pair_pos    = (int*)alloc(NPAIR * 4);
  ushort_t* Xb  = (ushort_t*)alloc((size_t)N_TOK * H_DIM * 2);
  ushort_t* Y   = (ushort_t*)alloc((size_t)NPAIR_PAD * FF_DIM * 2);
  ushort_t* w2b = (ushort_t*)alloc((size_t)N_EXP * H_DIM * FF_DIM * 2);
  // alias: w1b is dead after gemm1; Yout (bf16) written by gemm2 afterwards (same stream).
  size_t region = (size_t)N_EXP * FF_DIM * H_DIM * 2;  // 64 MB >= Yout's 33.8 MB
  char* rg = (char*)alloc(region);
  ushort_t* w1b  = (ushort_t*)rg;
  ushort_t* Yout = (ushort_t*)rg;

  hipMemsetAsync(counts, 0, N_EXP * 4, stream);
  convert_bf16_kernel<<<(N_TOK * H_DIM / 8 + 255) / 256, 256, 0, stream>>>(
      hidden, Xb, N_TOK * H_DIM / 8);
  convert_bf16_kernel<<<(N_EXP * FF_DIM * H_DIM / 8 + 255) / 256, 256, 0, stream>>>(
      w1, w1b, N_EXP * FF_DIM * H_DIM / 8);
  convert_bf16_kernel<<<(N_EXP * H_DIM * FF_DIM / 8 + 255) / 256, 256, 0, stream>>>(
      w2, w2b, N_EXP * H_DIM * FF_DIM / 8);
  router_kernel<<<N_TOK, 64, 0, stream>>>(hidden, rw, rb, tki, tkw, counts);
  offsets_kernel<<<1, 64, 0, stream>>>(counts, offsets, cursors);
  place_kernel<<<N_TOK / 256, 256, 0, stream>>>(tki, tkw, cursors, pair_token, pair_w, pair_pos);
  gemm1_kernel<<<dim3(FF_DIM / BN, (N_TOK + BM - 1) / BM, N_EXP), 256, 0, stream>>>(
      Xb, w1b, b1, pair_token, offsets, Y);
  gemm2_kernel<<<dim3(H_DIM / BN, (N_TOK + BM - 1) / BM, N_EXP), 256, 0, stream>>>(
      Y, w2b, b2, pair_w, offsets, Yout);
  ln_kernel<<<N_TOK, 256, 0, stream>>>(hidden, Yout, pair_pos, lnw, lnb, out);
}

// Round 4
// 842.487 us; speedup vs baseline: 2.1941x; 1.2851x over previous
//
#include <hip/hip_runtime.h>
#include <hip/hip_bf16.h>
#include <math.h>

#define N_TOK 8192
#define H_DIM 1024
#define FF_DIM 4096
#define N_EXP 8
#define NPAIR (N_TOK * 2)
#define NPAIR_PAD (NPAIR + 128)
#define RBLK 32          // routing blocks (256 tokens each)

#define BM 128
#define BN 128
#define BK 64   // bf16 elems; tile = 128x64x2B = 16 KB, two tiles = 32 KB LDS

typedef unsigned short ushort_t;
typedef short shortx8 __attribute__((ext_vector_type(8)));
typedef float floatx4 __attribute__((ext_vector_type(4)));

__device__ inline unsigned short f2b(float f) {
  unsigned int u = __float_as_uint(f);
  u += 0x7fffu + ((u >> 16) & 1u);
  return (unsigned short)(u >> 16);
}

__device__ inline float b2f(ushort_t b) {
  return __uint_as_float(((unsigned int)b) << 16);
}

// tanh-approx GELU: max |err| vs exact erf-gelu ~3e-4, ~10 VALU ops.
__device__ inline float fast_gelu(float x) {
  float u = 0.7978845608f * x * (1.f + 0.044715f * x * x);
  float au = fabsf(u);
  float e = __expf(-2.f * au);
  float t = (1.f - e) / (1.f + e);       // tanh(|u|)
  t = copysignf(t, u);
  return 0.5f * x * (1.f + t);
}

// async global->LDS, 16B per lane. LDS dest must be wave-uniform base; HW adds lane*16.
__device__ inline void async16(const void* g, void* l) {
  __builtin_amdgcn_global_load_lds(
      (const __attribute__((address_space(1))) unsigned int*)g,
      (__attribute__((address_space(3))) unsigned int*)l, 16, 0, 0);
}

// ---------- fp32 -> bf16 convert (hidden / w1 / w2) ----------
__global__ void convert_bf16_kernel(const float* __restrict__ src,
                                    ushort_t* __restrict__ dst, int n8) {
  int i = blockIdx.x * blockDim.x + threadIdx.x;
  if (i >= n8) return;
  const float4* s = (const float4*)(src + (size_t)i * 8);
  float4 a = s[0], b = s[1];
  ushort4 lo, hi;
  lo.x = f2b(a.x); lo.y = f2b(a.y); lo.z = f2b(a.z); lo.w = f2b(a.w);
  hi.x = f2b(b.x); hi.y = f2b(b.y); hi.z = f2b(b.z); hi.w = f2b(b.w);
  ushort4* d = (ushort4*)(dst + (size_t)i * 8);
  d[0] = lo; d[1] = hi;
}

// ---------- router: logits, top-2, softmax (NO atomics) ----------
__global__ void router_kernel(const float* __restrict__ x, const float* __restrict__ rw,
                              const float* __restrict__ rb, int* __restrict__ tki,
                              float* __restrict__ tkw) {
  int t = blockIdx.x;
  int lane = threadIdx.x;
  const float* xr = x + (size_t)t * H_DIM;
  float p[N_EXP];
#pragma unroll
  for (int e = 0; e < N_EXP; e++) p[e] = 0.f;
  for (int h = lane; h < H_DIM; h += 64) {
    float xv = xr[h];
#pragma unroll
    for (int e = 0; e < N_EXP; e++) p[e] += xv * rw[e * H_DIM + h];
  }
#pragma unroll
  for (int m = 1; m < 64; m <<= 1) {
#pragma unroll
    for (int e = 0; e < N_EXP; e++) p[e] += __shfl_xor(p[e], m, 64);
  }
  if (lane == 0) {
#pragma unroll
    for (int e = 0; e < N_EXP; e++) p[e] += rb[e];
    int i0 = 0; float v0 = p[0];
#pragma unroll
    for (int e = 1; e < N_EXP; e++) if (p[e] > v0) { v0 = p[e]; i0 = e; }
    int i1 = -1; float v1 = -1e30f;
#pragma unroll
    for (int e = 0; e < N_EXP; e++) if (e != i0 && p[e] > v1) { v1 = p[e]; i1 = e; }
    float ex = expf(v1 - v0);
    float inv = 1.f / (1.f + ex);
    tki[2 * t] = i0; tki[2 * t + 1] = i1;
    tkw[2 * t] = inv; tkw[2 * t + 1] = ex * inv;
  }
}

// ---------- per-block expert histogram (LDS atomics only) ----------
__global__ void count_kernel(const int* __restrict__ tki, int* __restrict__ counts_blk) {
  __shared__ int hist[N_EXP];
  int tid = threadIdx.x;
  if (tid < N_EXP) hist[tid] = 0;
  __syncthreads();
  int t = blockIdx.x * 256 + tid;
  int e0 = tki[2 * t], e1 = tki[2 * t + 1];
  atomicAdd(&hist[e0], 1);
  atomicAdd(&hist[e1], 1);
  __syncthreads();
  if (tid < N_EXP) counts_blk[blockIdx.x * N_EXP + tid] = hist[tid];
}

// ---------- global expert offsets + per-block cursors ----------
__global__ void offsets_kernel(const int* __restrict__ counts_blk, int* __restrict__ offsets,
                               int* __restrict__ start) {
  __shared__ int ec[RBLK * N_EXP];     // [block][expert]
  __shared__ int sle[RBLK * N_EXP];    // exclusive scan over blocks, per expert
  __shared__ int total[N_EXP];
  __shared__ int eoff[N_EXP + 1];
  int tid = threadIdx.x;
  if (tid < RBLK * N_EXP) ec[tid] = counts_blk[tid];
  __syncthreads();
  if (tid < N_EXP) {
    int run = 0;
    for (int b = 0; b < RBLK; b++) {
      sle[b * N_EXP + tid] = run;
      run += ec[b * N_EXP + tid];
    }
    total[tid] = run;
  }
  __syncthreads();
  if (tid == 0) {
    int off = 0;
    for (int e = 0; e < N_EXP; e++) { eoff[e] = off; off += total[e]; }
    eoff[N_EXP] = off;
  }
  __syncthreads();
  if (tid < N_EXP + 1) offsets[tid] = eoff[tid];
  if (tid < RBLK * N_EXP) {
    int e = tid % N_EXP;
    start[tid] = eoff[e] + sle[tid];
  }
}

// ---------- build per-expert pair lists (LDS cursors, no global atomics) ----------
__global__ void place_kernel(const int* __restrict__ tki, const float* __restrict__ tkw,
                             const int* __restrict__ start, int* __restrict__ pair_token,
                             float* __restrict__ pair_w, int* __restrict__ pair_pos) {
  __shared__ int cur[N_EXP];
  int tid = threadIdx.x;
  if (tid < N_EXP) cur[tid] = start[blockIdx.x * N_EXP + tid];
  __syncthreads();
  int t = blockIdx.x * 256 + tid;
#pragma unroll
  for (int k = 0; k < 2; k++) {
    int e = tki[2 * t + k];
    int pos = atomicAdd(&cur[e], 1);
    pair_token[pos] = t;
    pair_w[pos] = tkw[2 * t + k];
    pair_pos[2 * t + k] = pos;
  }
}

// ---------- GEMM1: Y = gelu(Xg @ w1[e]^T + b1[e]) ----------
// LDS layout: 16B chunks; chunk (row, c) holds global k-chunk (c ^ (row&7)).
// Staging via global_load_lds is contiguous per wave; ds_read_b128 lands 2-way max.
__global__ __launch_bounds__(256, 2)
void gemm1_kernel(const ushort_t* __restrict__ Xb, const ushort_t* __restrict__ w1b,
                  const float* __restrict__ b1, const int* __restrict__ pair_token,
                  const int* __restrict__ offsets, ushort_t* __restrict__ Y) {
  int e = blockIdx.z;
  int off = offsets[e];
  int cnt = offsets[e + 1] - off;
  int m0 = blockIdx.y * BM;
  if (m0 >= cnt) return;
  int n0 = blockIdx.x * BN;

  __shared__ ushort_t As[BM * BK];
  __shared__ ushort_t Bs[BN * BK];

  int tid = threadIdx.x;
  int w = tid >> 6, l = tid & 63;
  int lr8 = l >> 3;                       // row-within-8 of this lane's 16B chunk
  int lcol = ((l & 7) ^ lr8) << 3;        // swizzled global k-chunk (elements)

  const ushort_t* gA[4];
  const ushort_t* gB[4];
  ushort_t* lA[4];
  ushort_t* lB[4];
#pragma unroll
  for (int it = 0; it < 4; it++) {
    int row = (w * 4 + it) * 8 + lr8;
    int m = m0 + row; if (m >= cnt) m = cnt - 1;
    int tok = pair_token[off + m];
    gA[it] = Xb + (size_t)tok * H_DIM + lcol;
    gB[it] = w1b + ((size_t)e * FF_DIM + n0 + row) * H_DIM + lcol;
    lA[it] = As + (w * 4 + it) * 512;
    lB[it] = Bs + (w * 4 + it) * 512;
  }

  floatx4 acc[4][4];
#pragma unroll
  for (int i = 0; i < 4; i++)
#pragma unroll
    for (int j = 0; j < 4; j++) acc[i][j] = (floatx4){0.f, 0.f, 0.f, 0.f};

  int wm = (w & 1) * 64, wn = (w >> 1) * 64;
  int lrow = l & 15, lq = l >> 4, sx = l & 7;

  for (int k0 = 0; k0 < H_DIM; k0 += BK) {
#pragma unroll
    for (int it = 0; it < 4; it++) async16(gA[it] + k0, lA[it]);
#pragma unroll
    for (int it = 0; it < 4; it++) async16(gB[it] + k0, lB[it]);
    __syncthreads();
#pragma unroll
    for (int kkh = 0; kkh < 2; kkh++) {
      int c = (((lq + 4 * kkh) ^ sx) << 3);
      shortx8 af[4], bf[4];
#pragma unroll
      for (int i = 0; i < 4; i++) {
        af[i] = *(const shortx8*)&As[(wm + i * 16 + lrow) * BK + c];
        bf[i] = *(const shortx8*)&Bs[(wn + i * 16 + lrow) * BK + c];
      }
#pragma unroll
      for (int i = 0; i < 4; i++)
#pragma unroll
        for (int j = 0; j < 4; j++)
          acc[i][j] = __builtin_amdgcn_mfma_f32_16x16x32_bf16(af[i], bf[j], acc[i][j], 0, 0, 0);
    }
    __syncthreads();
  }

  // epilogue: bias + fast gelu -> bf16 Y
#pragma unroll
  for (int j = 0; j < 4; j++) {
    int col = n0 + wn + j * 16 + lrow;
    float bias = b1[(size_t)e * FF_DIM + col];
#pragma unroll
    for (int i = 0; i < 4; i++) {
#pragma unroll
      for (int r = 0; r < 4; r++) {
        int rm = wm + i * 16 + lq * 4 + r;
        if (m0 + rm < cnt) {
          float v = fast_gelu(acc[i][j][r] + bias);
          Y[(size_t)(off + m0 + rm) * FF_DIM + col] = f2b(v);
        }
      }
    }
  }
}

// ---------- GEMM2: Yout(bf16) = (Y @ w2[e]^T + b2[e]) * pair_w ----------
__global__ __launch_bounds__(256, 2)
void gemm2_kernel(const ushort_t* __restrict__ Y, const ushort_t* __restrict__ w2b,
                  const float* __restrict__ b2, const float* __restrict__ pair_w,
                  const int* __restrict__ offsets, ushort_t* __restrict__ Yout) {
  int e = blockIdx.z;
  int off = offsets[e];
  int cnt = offsets[e + 1] - off;
  int m0 = blockIdx.y * BM;
  if (m0 >= cnt) return;
  int n0 = blockIdx.x * BN;

  __shared__ ushort_t As[BM * BK];
  __shared__ ushort_t Bs[BN * BK];

  int tid = threadIdx.x;
  int w = tid >> 6, l = tid & 63;
  int lr8 = l >> 3;
  int lcol = ((l & 7) ^ lr8) << 3;

  const ushort_t* gA[4];
  const ushort_t* gB[4];
  ushort_t* lA[4];
  ushort_t* lB[4];
#pragma unroll
  for (int it = 0; it < 4; it++) {
    int row = (w * 4 + it) * 8 + lr8;
    gA[it] = Y + (size_t)(off + m0 + row) * FF_DIM + lcol;   // pad rows safe: NPAIR_PAD slack
    gB[it] = w2b + ((size_t)e * H_DIM + n0 + row) * FF_DIM + lcol;
    lA[it] = As + (w * 4 + it) * 512;
    lB[it] = Bs + (w * 4 + it) * 512;
  }

  floatx4 acc[4][4];
#pragma unroll
  for (int i = 0; i < 4; i++)
#pragma unroll
    for (int j = 0; j < 4; j++) acc[i][j] = (floatx4){0.f, 0.f, 0.f, 0.f};

  int wm = (w & 1) * 64, wn = (w >> 1) * 64;
  int lrow = l & 15, lq = l >> 4, sx = l & 7;

  for (int k0 = 0; k0 < FF_DIM; k0 += BK) {
#pragma unroll
    for (int it = 0; it < 4; it++) async16(gA[it] + k0, lA[it]);
#pragma unroll
    for (int it = 0; it < 4; it++) async16(gB[it] + k0, lB[it]);
    __syncthreads();
#pragma unroll
    for (int kkh = 0; kkh < 2; kkh++) {
      int c = (((lq + 4 * kkh) ^ sx) << 3);
      shortx8 af[4], bf[4];
#pragma unroll
      for (int i = 0; i < 4; i++) {
        af[i] = *(const shortx8*)&As[(wm + i * 16 + lrow) * BK + c];
        bf[i] = *(const shortx8*)&Bs[(wn + i * 16 + lrow) * BK + c];
      }
#pragma unroll
      for (int i = 0; i < 4; i++)
#pragma unroll
        for (int j = 0; j < 4; j++)
          acc[i][j] = __builtin_amdgcn_mfma_f32_16x16x32_bf16(af[i], bf[j], acc[i][j], 0, 0, 0);
    }
    __syncthreads();
  }

#pragma unroll
  for (int j = 0; j < 4; j++) {
    int col = n0 + wn + j * 16 + lrow;
    float bias = b2[(size_t)e * H_DIM + col];
#pragma unroll
    for (int i = 0; i < 4; i++) {
#pragma unroll
      for (int r = 0; r < 4; r++) {
        int rm = wm + i * 16 + lq * 4 + r;
        if (m0 + rm < cnt) {
          int p = off + m0 + rm;
          float v = (acc[i][j][r] + bias) * pair_w[p];
          Yout[(size_t)p * H_DIM + col] = f2b(v);
        }
      }
    }
  }
}

// ---------- final: residual + combine 2 experts + layernorm ----------
__global__ void ln_kernel(const float* __restrict__ hidden, const ushort_t* __restrict__ Yout,
                          const int* __restrict__ pair_pos, const float* __restrict__ lnw,
                          const float* __restrict__ lnb, float* __restrict__ out) {
  int t = blockIdx.x;
  int tid = threadIdx.x;   // 256 threads, 4 floats each
  int p0 = pair_pos[2 * t], p1 = pair_pos[2 * t + 1];
  float4 hv = ((const float4*)(hidden + (size_t)t * H_DIM))[tid];
  ushort4 au = ((const ushort4*)(Yout + (size_t)p0 * H_DIM))[tid];
  ushort4 bu = ((const ushort4*)(Yout + (size_t)p1 * H_DIM))[tid];
  float x0 = hv.x + b2f(au.x) + b2f(bu.x);
  float x1 = hv.y + b2f(au.y) + b2f(bu.y);
  float x2 = hv.z + b2f(au.z) + b2f(bu.z);
  float x3 = hv.w + b2f(au.w) + b2f(bu.w);
  float s = x0 + x1 + x2 + x3;
  float ss = x0 * x0 + x1 * x1 + x2 * x2 + x3 * x3;
#pragma unroll
  for (int m = 1; m < 64; m <<= 1) {
    s += __shfl_xor(s, m, 64);
    ss += __shfl_xor(ss, m, 64);
  }
  __shared__ float red[8];
  int wave = tid >> 6, lane = tid & 63;
  if (lane == 0) { red[wave] = s; red[wave + 4] = ss; }
  __syncthreads();
  s = red[0] + red[1] + red[2] + red[3];
  ss = red[4] + red[5] + red[6] + red[7];
  float mu = s * (1.f / H_DIM);
  float var = ss * (1.f / H_DIM) - mu * mu;
  float rstd = rsqrtf(var + 1e-12f);
  int h = tid * 4;
  float4 o;
  o.x = (x0 - mu) * rstd * lnw[h + 0] + lnb[h + 0];
  o.y = (x1 - mu) * rstd * lnw[h + 1] + lnb[h + 1];
  o.z = (x2 - mu) * rstd * lnw[h + 2] + lnb[h + 2];
  o.w = (x3 - mu) * rstd * lnw[h + 3] + lnb[h + 3];
  ((float4*)(out + (size_t)t * H_DIM))[tid] = o;
}

extern "C" void kernel_launch(void* const* d_in, const int* in_sizes, int n_in,
                              void* d_out, int out_size, void* d_ws, size_t ws_size,
                              hipStream_t stream) {
  const float* hidden = (const float*)d_in[0];
  const float* rw     = (const float*)d_in[1];
  const float* rb     = (const float*)d_in[2];
  const float* w1     = (const float*)d_in[3];
  const float* b1     = (const float*)d_in[4];
  const float* w2     = (const float*)d_in[5];
  const float* b2     = (const float*)d_in[6];
  const float* lnw    = (const float*)d_in[7];
  const float* lnb    = (const float*)d_in[8];
  float* out = (float*)d_out;

  char* base = (char*)d_ws;
  size_t cur = 0;
  auto alloc = [&](size_t bytes) -> void* {
    void* r = base + cur;
    cur = (cur + bytes + 255) & ~(size_t)255;
    return r;
  };
  int* counts_blk  = (int*)alloc(RBLK * N_EXP * 4);
  int* offsets     = (int*)alloc((N_EXP + 1) * 4);
  int* start       = (int*)alloc(RBLK * N_EXP * 4);
  int* tki         = (int*)alloc(NPAIR * 4);
  float* tkw       = (float*)alloc(NPAIR * 4);
  int* pair_token  = (int*)alloc(NPAIR_PAD * 4);
  float* pair_w    = (float*)alloc(NPAIR_PAD * 4);
  int* pair_pos    = (int*)alloc(NPAIR * 4);
  ushort_t* Xb  = (ushort_t*)alloc((size_t)N_TOK * H_DIM * 2);
  ushort_t* Y   = (ushort_t*)alloc((size_t)NPAIR_PAD * FF_DIM * 2);
  ushort_t* w2b = (ushort_t*)alloc((size_t)N_EXP * H_DIM * FF_DIM * 2);
  // alias: w1b is dead after gemm1; Yout (bf16) written by gemm2 afterwards (same stream).
  size_t region = (size_t)N_EXP * FF_DIM * H_DIM * 2;  // 64 MB >= Yout's 33.8 MB
  char* rg = (char*)alloc(region);
  ushort_t* w1b  = (ushort_t*)rg;
  ushort_t* Yout = (ushort_t*)rg;

  convert_bf16_kernel<<<(N_TOK * H_DIM / 8 + 255) / 256, 256, 0, stream>>>(
      hidden, Xb, N_TOK * H_DIM / 8);
  convert_bf16_kernel<<<(N_EXP * FF_DIM * H_DIM / 8 + 255) / 256, 256, 0, stream>>>(
      w1, w1b, N_EXP * FF_DIM * H_DIM / 8);
  convert_bf16_kernel<<<(N_EXP * H_DIM * FF_DIM / 8 + 255) / 256, 256, 0, stream>>>(
      w2, w2b, N_EXP * H_DIM * FF_DIM / 8);
  router_kernel<<<N_TOK, 64, 0, stream>>>(hidden, rw, rb, tki, tkw);
  count_kernel<<<RBLK, 256, 0, stream>>>(tki, counts_blk);
  offsets_kernel<<<1, 256, 0, stream>>>(counts_blk, offsets, start);
  place_kernel<<<RBLK, 256, 0, stream>>>(tki, tkw, start, pair_token, pair_w, pair_pos);
  gemm1_kernel<<<dim3(FF_DIM / BN, (N_TOK + BM - 1) / BM, N_EXP), 256, 0, stream>>>(
      Xb, w1b, b1, pair_token, offsets, Y);
  gemm2_kernel<<<dim3(H_DIM / BN, (N_TOK + BM - 1) / BM, N_EXP), 256, 0, stream>>>(
      Y, w2b, b2, pair_w, offsets, Yout);
  ln_kernel<<<N_TOK, 256, 0, stream>>>(hidden, Yout, pair_pos, lnw, lnb, out);
}